// Round 17
// baseline (135.128 us; speedup 1.0000x reference)
//
#include <hip/hip_runtime.h>
#include <math.h>

#define B_ 4096
#define T_ 64
#define V_ 512
#define E_ 32
#define H_ 128
#define FC1_ 256
#define O_ 1024

typedef float f32x4 __attribute__((ext_vector_type(4)));
typedef short s16x8 __attribute__((ext_vector_type(8)));
typedef unsigned short u16;

#define MFMA16(a, b, c) __builtin_amdgcn_mfma_f32_16x16x32_bf16(a, b, c, 0, 0, 0)

// LDS-only barrier (do not drain vmcnt; global prefetch stays in flight)
#define LDS_BARRIER() do {                                   \
    asm volatile("s_waitcnt lgkmcnt(0)" ::: "memory");       \
    __builtin_amdgcn_s_barrier();                            \
} while (0)

union Frag { u16 q[8]; unsigned u[4]; s16x8 v; };

__device__ __forceinline__ u16 f2bf(float f) {
    union { float f; unsigned u; } v; v.f = f;
    unsigned r = v.u + 0x7FFFu + ((v.u >> 16) & 1u);   // RNE
    return (u16)(r >> 16);
}
__device__ __forceinline__ unsigned cvtpk(float lo, float hi) {
    unsigned r;
    asm("v_cvt_pk_bf16_f32 %0, %1, %2" : "=v"(r) : "v"(lo), "v"(hi));
    return r;
}
__device__ __forceinline__ float sigf(float x) { return 1.0f / (1.0f + __expf(-x)); }
__device__ __forceinline__ float tanhfast(float x) {
    return 1.0f - 2.0f / (__expf(2.0f * x) + 1.0f);
}

// ---------------- prep: pack all weights into MFMA B-fragment layout (bf16) ----
__global__ void __launch_bounds__(256) prep_kernel(
    const float* __restrict__ Wih, const float* __restrict__ Whh,
    const float* __restrict__ Wemb, const float* __restrict__ Wfc1,
    const float* __restrict__ Wfc2,
    u16* __restrict__ wihF, u16* __restrict__ whhF, u16* __restrict__ wembF,
    u16* __restrict__ wfc1F, u16* __restrict__ wfc2F) {
    int id = blockIdx.x * 256 + threadIdx.x;
    int np = gridDim.x * 256;
    for (int i = id; i < 24 * 4 * 64 * 8; i += np) {       // W_hh [384][128]
        int j = i & 7, l = (i >> 3) & 63, kc = (i >> 9) & 3, gt = i >> 11;
        whhF[i] = f2bf(Whh[(gt * 16 + (l & 15)) * 128 + kc * 32 + (l >> 4) * 8 + j]);
    }
    for (int i = id; i < 24 * 64 * 8; i += np) {           // W_ih [384][32]
        int j = i & 7, l = (i >> 3) & 63, gt = i >> 9;
        wihF[i] = f2bf(Wih[(gt * 16 + (l & 15)) * 32 + (l >> 4) * 8 + j]);
    }
    for (int i = id; i < 2 * 16 * 64 * 8; i += np) {       // W_emb [32][512]
        int j = i & 7, l = (i >> 3) & 63, kc = (i >> 9) & 15, nt = i >> 13;
        wembF[i] = f2bf(Wemb[(nt * 16 + (l & 15)) * 512 + kc * 32 + (l >> 4) * 8 + j]);
    }
    for (int i = id; i < 16 * 4 * 64 * 8; i += np) {       // W_fc1 [256][128]
        int j = i & 7, l = (i >> 3) & 63, kc = (i >> 9) & 3, ot = i >> 11;
        wfc1F[i] = f2bf(Wfc1[(ot * 16 + (l & 15)) * 128 + kc * 32 + (l >> 4) * 8 + j]);
    }
    for (int i = id; i < 64 * 8 * 64 * 8; i += np) {       // W_fc2 [1024][256]
        int j = i & 7, l = (i >> 3) & 63, kc = (i >> 9) & 7, nt = i >> 12;
        wfc2F[i] = f2bf(Wfc2[(nt * 16 + (l & 15)) * 256 + kc * 32 + (l >> 4) * 8 + j]);
    }
}

// ---------------- fused embed + GRU + FC1 + FC2 -------------------------------
// 256 blocks x 512 threads (8 waves); block owns 16 batch rows.
// ONE barrier per step; x pipelined 2 steps ahead (epart/xfrag dbufs).
// Msg loads: per-thread register prefetch, 4-buffer rotation, 3-4 steps ahead.
// R17: gate accumulators chain-split (depth 5 -> 3) + setprio around MFMA block.
__global__ void __launch_bounds__(512, 2) fused_kernel(
    const float* __restrict__ msg,
    const u16* __restrict__ whhF8, const u16* __restrict__ wihF8,
    const u16* __restrict__ wembF8,
    const float* __restrict__ b_ih, const float* __restrict__ b_hh,
    const float* __restrict__ b_emb, const float* __restrict__ init_emb,
    const u16* __restrict__ wfc1F8, const float* __restrict__ b_fc1,
    const u16* __restrict__ wfc2F8, const float* __restrict__ b_fc2,
    float* __restrict__ out) {
    __shared__ u16 hlds[2][16 * 136];     // h double buffer, row stride 136
    __shared__ float epart[2][8][576];    // embed partials, dbuf, row stride 36
    __shared__ u16 xfrag[2][640];         // x bf16 A-frag staging, row stride 40
    __shared__ u16 hidl[16 * 264];        // FC1 out
    const int tid = threadIdx.x, w = tid >> 6, l = tid & 63;
    const int ln = l & 15, lh = l >> 4;
    const int wg = w & 3, wp = w >> 2;
    const int gb = blockIdx.x;

    for (int i = tid; i < 16 * 136; i += 512) hlds[0][i] = 0;

    // ---- resident weight fragments ----
    const s16x8* whhFv = (const s16x8*)whhF8;
    const s16x8* wihFv = (const s16x8*)wihF8;
    const s16x8* wembFv = (const s16x8*)wembF8;
    s16x8 wh[3][4], wi[3], we[2][2];
    float br, bz, bin, bgn;
    {
        #pragma unroll
        for (int g = 0; g < 3; g++) {
            int gt = wg + 4 * wp + 8 * g;
            #pragma unroll
            for (int kc = 0; kc < 4; kc++) wh[g][kc] = whhFv[(gt * 4 + kc) * 64 + l];
            wi[g] = wihFv[gt * 64 + l];
        }
        int c = wg * 16 + wp * 64 + ln;
        br  = b_ih[c] + b_hh[c];
        bz  = b_ih[128 + c] + b_hh[128 + c];
        bin = b_ih[256 + c];
        bgn = b_hh[256 + c];
        #pragma unroll
        for (int kk = 0; kk < 2; kk++) {
            we[kk][0] = wembFv[(2 * w + kk) * 64 + l];
            we[kk][1] = wembFv[(16 + 2 * w + kk) * 64 + l];
        }
    }
    const float bev = b_emb[tid & 31];

    // x_0 = init_emb broadcast (A-frag: lane l holds x[*][lh*8+j])
    s16x8 xinit;
    {
        Frag xi;
        #pragma unroll
        for (int j = 0; j < 8; j++) xi.q[j] = f2bf(init_emb[lh * 8 + j]);
        xinit = xi.v;
    }
    float hold[4] = {};
    // msg base: row (gb*16+ln), float offset (2w)*32 + lh*8
    const float* mrow = msg + (size_t)(gb * 16 + ln) * T_ * V_ + (2 * w) * 32 + lh * 8;
    f32x4 mb0[4], mb1[4], mb2[4], mb3[4];
#define LOADCOL(BUF, C) do {                                   \
    const float* p_ = mrow + (size_t)(C) * 512;                \
    BUF[0] = *(const f32x4*)(p_);                              \
    BUF[1] = *(const f32x4*)(p_ + 4);                          \
    BUF[2] = *(const f32x4*)(p_ + 32);                         \
    BUF[3] = *(const f32x4*)(p_ + 36);                         \
} while (0)

// embed partials of one msg column (held in MC regs) -> epart[PAR][w]
#define EMBED_STORE(MC, PAR) do {                               \
    f32x4 e0 = {0.f, 0.f, 0.f, 0.f}, e1 = {0.f, 0.f, 0.f, 0.f}; \
    _Pragma("unroll")                                           \
    for (int kk = 0; kk < 2; kk++) {                            \
        Frag fa;                                                \
        fa.u[0] = cvtpk(MC[2 * kk][0], MC[2 * kk][1]);          \
        fa.u[1] = cvtpk(MC[2 * kk][2], MC[2 * kk][3]);          \
        fa.u[2] = cvtpk(MC[2 * kk + 1][0], MC[2 * kk + 1][1]);  \
        fa.u[3] = cvtpk(MC[2 * kk + 1][2], MC[2 * kk + 1][3]);  \
        e0 = MFMA16(fa.v, we[kk][0], e0);                       \
        e1 = MFMA16(fa.v, we[kk][1], e1);                       \
    }                                                           \
    _Pragma("unroll")                                           \
    for (int i = 0; i < 4; i++) {                               \
        epart[PAR][w][(lh * 4 + i) * 36 + ln]      = e0[i];     \
        epart[PAR][w][(lh * 4 + i) * 36 + 16 + ln] = e1[i];     \
    }                                                           \
} while (0)

    // ---- prologue: partials of x_1 = emb(msg col 0) -> epart[1]; preload cols 1-3
    LOADCOL(mb3, 0);
    EMBED_STORE(mb3, 1);
    LOADCOL(mb0, 1); LOADCOL(mb1, 2); LOADCOL(mb2, 3);
    LDS_BARRIER();

    const int aoff = ln * 136 + lh * 8;
    const int colo = wg * 16 + wp * 64 + ln;
    const int fr = tid >> 5, fc = tid & 31, fo = fr * 36 + fc;

#define GRU_STEP(TT, MC, MN) do {                                              \
    const int t = (TT);                                                        \
    if (t <= 58) LOADCOL(MN, t + 4);                                           \
    const u16* hb = hlds[t & 1];                                               \
    s16x8 af0 = *(const s16x8*)(hb + aoff);                                    \
    s16x8 af1 = *(const s16x8*)(hb + aoff + 32);                               \
    s16x8 af2 = *(const s16x8*)(hb + aoff + 64);                               \
    s16x8 af3 = *(const s16x8*)(hb + aoff + 96);                               \
    s16x8 xc;                                                                  \
    if (t == 0) xc = xinit;                                                    \
    else xc = *(const s16x8*)(&xfrag[(t + 1) & 1][0] + ln * 40 + lh * 8);      \
    f32x4 ar  = {br, br, br, br};                                              \
    f32x4 az  = {bz, bz, bz, bz};                                              \
    f32x4 agn = {bgn, bgn, bgn, bgn};                                          \
    f32x4 ain = {bin, bin, bin, bin};                                          \
    f32x4 zz  = {0.f, 0.f, 0.f, 0.f};                                          \
    f32x4 arB = zz, azB = zz, agnB = zz;                                       \
    __builtin_amdgcn_s_setprio(1);                                             \
    ar  = MFMA16(xc, wi[0], ar);                                               \
    az  = MFMA16(xc, wi[1], az);                                               \
    ain = MFMA16(xc, wi[2], ain);                                              \
    ar  = MFMA16(af0, wh[0][0], ar);                                           \
    az  = MFMA16(af0, wh[1][0], az);                                           \
    agn = MFMA16(af0, wh[2][0], agn);                                          \
    ar  = MFMA16(af1, wh[0][1], ar);                                           \
    az  = MFMA16(af1, wh[1][1], az);                                           \
    agn = MFMA16(af1, wh[2][1], agn);                                          \
    arB  = MFMA16(af2, wh[0][2], arB);                                         \
    azB  = MFMA16(af2, wh[1][2], azB);                                         \
    agnB = MFMA16(af2, wh[2][2], agnB);                                        \
    arB  = MFMA16(af3, wh[0][3], arB);                                         \
    azB  = MFMA16(af3, wh[1][3], azB);                                         \
    agnB = MFMA16(af3, wh[2][3], agnB);                                        \
    __builtin_amdgcn_s_setprio(0);                                             \
    ar  += arB;                                                                \
    az  += azB;                                                                \
    agn += agnB;                                                               \
    u16* hw = hlds[(t + 1) & 1];                                               \
    float hn[4];                                                               \
    _Pragma("unroll")                                                          \
    for (int i = 0; i < 4; i++) {                                              \
        float rg = sigf(ar[i]);                                                \
        float zg = sigf(az[i]);                                                \
        float ng = tanhfast(ain[i] + rg * agn[i]);                             \
        hn[i] = zg * (hold[i] - ng) + ng;                                      \
        hold[i] = hn[i];                                                       \
    }                                                                          \
    {                                                                          \
        unsigned u01 = cvtpk(hn[0], hn[1]);                                    \
        unsigned u23 = cvtpk(hn[2], hn[3]);                                    \
        hw[(lh * 4 + 0) * 136 + colo] = (u16)(u01 & 0xFFFFu);                  \
        hw[(lh * 4 + 1) * 136 + colo] = (u16)(u01 >> 16);                      \
        hw[(lh * 4 + 2) * 136 + colo] = (u16)(u23 & 0xFFFFu);                  \
        hw[(lh * 4 + 3) * 136 + colo] = (u16)(u23 >> 16);                      \
    }                                                                          \
    if (t <= 61) EMBED_STORE(MC, t & 1);                                       \
    if (t <= 62) {                                                             \
        const float* eb = &epart[(t + 1) & 1][0][0];                           \
        float s = eb[fo]           + eb[576 + fo]     + eb[2 * 576 + fo]       \
                + eb[3 * 576 + fo] + eb[4 * 576 + fo] + eb[5 * 576 + fo]       \
                + eb[6 * 576 + fo] + eb[7 * 576 + fo] + bev;                   \
        xfrag[t & 1][fr * 40 + fc] = f2bf(s);                                  \
    }                                                                          \
    LDS_BARRIER();                                                             \
} while (0)

    for (int tt = 0; tt < 64; tt += 4) {
        GRU_STEP(tt + 0, mb0, mb3);
        GRU_STEP(tt + 1, mb1, mb0);
        GRU_STEP(tt + 2, mb2, mb1);
        GRU_STEP(tt + 3, mb3, mb2);
    }
#undef GRU_STEP
#undef LOADCOL
#undef EMBED_STORE

    // ---- FC1: hid = elu(h @ W_fc1^T + b_fc1), [16][256]; wave w: ot = 2w,2w+1
    const u16* hb = hlds[0];   // final h in buffer (63+1)&1 = 0
    s16x8 hf0 = *(const s16x8*)(hb + aoff);
    s16x8 hf1 = *(const s16x8*)(hb + aoff + 32);
    s16x8 hf2 = *(const s16x8*)(hb + aoff + 64);
    s16x8 hf3 = *(const s16x8*)(hb + aoff + 96);
    const s16x8* w1v = (const s16x8*)wfc1F8;
    #pragma unroll
    for (int q = 0; q < 2; q++) {
        int ot = 2 * w + q;
        float b1 = b_fc1[ot * 16 + ln];
        f32x4 a1 = {b1, b1, b1, b1};
        a1 = MFMA16(hf0, w1v[(ot * 4 + 0) * 64 + l], a1);
        a1 = MFMA16(hf1, w1v[(ot * 4 + 1) * 64 + l], a1);
        a1 = MFMA16(hf2, w1v[(ot * 4 + 2) * 64 + l], a1);
        a1 = MFMA16(hf3, w1v[(ot * 4 + 3) * 64 + l], a1);
        #pragma unroll
        for (int i = 0; i < 4; i++) {
            float v = a1[i];
            v = v > 0.0f ? v : (__expf(v) - 1.0f);
            hidl[(lh * 4 + i) * 264 + ot * 16 + ln] = f2bf(v);
        }
    }
    LDS_BARRIER();

    // ---- FC2: out = sigmoid(hid @ W_fc2^T + b_fc2); wave w: nt = 8w..8w+7
    s16x8 hf[8];
    #pragma unroll
    for (int kc = 0; kc < 8; kc++)
        hf[kc] = *(const s16x8*)(hidl + ln * 264 + kc * 32 + lh * 8);
    const s16x8* w2v = (const s16x8*)wfc2F8;
    #pragma unroll
    for (int q = 0; q < 8; q++) {
        int nt = 8 * w + q;
        float b2 = b_fc2[nt * 16 + ln];
        f32x4 a2 = {b2, b2, b2, b2};
        #pragma unroll
        for (int kc = 0; kc < 8; kc++)
            a2 = MFMA16(hf[kc], w2v[(nt * 8 + kc) * 64 + l], a2);
        #pragma unroll
        for (int i = 0; i < 4; i++)
            out[(size_t)(gb * 16 + lh * 4 + i) * 1024 + nt * 16 + ln] = sigf(a2[i]);
    }
}

extern "C" void kernel_launch(void* const* d_in, const int* in_sizes, int n_in,
                              void* d_out, int out_size, void* d_ws, size_t ws_size,
                              hipStream_t stream) {
    const float* message  = (const float*)d_in[0];
    const float* W_emb    = (const float*)d_in[1];
    const float* b_emb    = (const float*)d_in[2];
    const float* init_emb = (const float*)d_in[3];
    const float* W_ih     = (const float*)d_in[4];
    const float* W_hh     = (const float*)d_in[5];
    const float* b_ih     = (const float*)d_in[6];
    const float* b_hh     = (const float*)d_in[7];
    const float* W_fc1    = (const float*)d_in[8];
    const float* b_fc1    = (const float*)d_in[9];
    const float* W_fc2    = (const float*)d_in[10];
    const float* b_fc2    = (const float*)d_in[11];
    float* out = (float*)d_out;

    u16* whhF  = (u16*)d_ws;            // 24*4*64*8 = 49,152
    u16* wihF  = whhF  + 49152;         // 24*64*8   = 12,288
    u16* wembF = wihF  + 12288;         // 2*16*64*8 = 16,384
    u16* wfc1F = wembF + 16384;         // 16*4*64*8 = 32,768
    u16* wfc2F = wfc1F + 32768;         // 64*8*64*8 = 262,144  (total ~0.75 MB)

    hipLaunchKernelGGL(prep_kernel, dim3(256), dim3(256), 0, stream,
                       W_ih, W_hh, W_emb, W_fc1, W_fc2, wihF, whhF, wembF, wfc1F, wfc2F);
    hipLaunchKernelGGL(fused_kernel, dim3(256), dim3(512), 0, stream,
                       message, whhF, wihF, wembF, b_ih, b_hh, b_emb, init_emb,
                       wfc1F, b_fc1, wfc2F, b_fc2, out);
}

// Round 18
// 131.174 us; speedup vs baseline: 1.0301x; 1.0301x over previous
//
#include <hip/hip_runtime.h>
#include <math.h>

#define B_ 4096
#define T_ 64
#define V_ 512
#define E_ 32
#define H_ 128
#define FC1_ 256
#define O_ 1024

typedef float f32x4 __attribute__((ext_vector_type(4)));
typedef short s16x8 __attribute__((ext_vector_type(8)));
typedef unsigned short u16;

#define MFMA16(a, b, c) __builtin_amdgcn_mfma_f32_16x16x32_bf16(a, b, c, 0, 0, 0)

// LDS-only barrier (do not drain vmcnt; global prefetch stays in flight)
#define LDS_BARRIER() do {                                   \
    asm volatile("s_waitcnt lgkmcnt(0)" ::: "memory");       \
    __builtin_amdgcn_s_barrier();                            \
} while (0)

union Frag { u16 q[8]; unsigned u[4]; s16x8 v; };

__device__ __forceinline__ u16 f2bf(float f) {
    union { float f; unsigned u; } v; v.f = f;
    unsigned r = v.u + 0x7FFFu + ((v.u >> 16) & 1u);   // RNE
    return (u16)(r >> 16);
}
__device__ __forceinline__ unsigned cvtpk(float lo, float hi) {
    unsigned r;
    asm("v_cvt_pk_bf16_f32 %0, %1, %2" : "=v"(r) : "v"(lo), "v"(hi));
    return r;
}
__device__ __forceinline__ float sigf(float x) { return 1.0f / (1.0f + __expf(-x)); }
__device__ __forceinline__ float tanhfast(float x) {
    return 1.0f - 2.0f / (__expf(2.0f * x) + 1.0f);
}

// ---------------- prep: pack all weights into MFMA B-fragment layout (bf16) ----
__global__ void __launch_bounds__(256) prep_kernel(
    const float* __restrict__ Wih, const float* __restrict__ Whh,
    const float* __restrict__ Wemb, const float* __restrict__ Wfc1,
    const float* __restrict__ Wfc2,
    u16* __restrict__ wihF, u16* __restrict__ whhF, u16* __restrict__ wembF,
    u16* __restrict__ wfc1F, u16* __restrict__ wfc2F) {
    int id = blockIdx.x * 256 + threadIdx.x;
    int np = gridDim.x * 256;
    for (int i = id; i < 24 * 4 * 64 * 8; i += np) {       // W_hh [384][128]
        int j = i & 7, l = (i >> 3) & 63, kc = (i >> 9) & 3, gt = i >> 11;
        whhF[i] = f2bf(Whh[(gt * 16 + (l & 15)) * 128 + kc * 32 + (l >> 4) * 8 + j]);
    }
    for (int i = id; i < 24 * 64 * 8; i += np) {           // W_ih [384][32]
        int j = i & 7, l = (i >> 3) & 63, gt = i >> 9;
        wihF[i] = f2bf(Wih[(gt * 16 + (l & 15)) * 32 + (l >> 4) * 8 + j]);
    }
    for (int i = id; i < 2 * 16 * 64 * 8; i += np) {       // W_emb [32][512]
        int j = i & 7, l = (i >> 3) & 63, kc = (i >> 9) & 15, nt = i >> 13;
        wembF[i] = f2bf(Wemb[(nt * 16 + (l & 15)) * 512 + kc * 32 + (l >> 4) * 8 + j]);
    }
    for (int i = id; i < 16 * 4 * 64 * 8; i += np) {       // W_fc1 [256][128]
        int j = i & 7, l = (i >> 3) & 63, kc = (i >> 9) & 3, ot = i >> 11;
        wfc1F[i] = f2bf(Wfc1[(ot * 16 + (l & 15)) * 128 + kc * 32 + (l >> 4) * 8 + j]);
    }
    for (int i = id; i < 64 * 8 * 64 * 8; i += np) {       // W_fc2 [1024][256]
        int j = i & 7, l = (i >> 3) & 63, kc = (i >> 9) & 7, nt = i >> 12;
        wfc2F[i] = f2bf(Wfc2[(nt * 16 + (l & 15)) * 256 + kc * 32 + (l >> 4) * 8 + j]);
    }
}

// ---------------- fused embed + GRU + FC1 + FC2 -------------------------------
// 256 blocks x 512 threads (8 waves); block owns 16 batch rows.
// ONE barrier per step. x is pipelined 2 steps ahead:
//   step t: (a) embed msg[t+1] -> epart[t&1]   (partials of x_{t+2})
//           (b) reduce epart[(t+1)&1]          (x_{t+1}) -> xfrag[t&1]
//           (c) read x_t from xfrag[(t+1)&1]   (written at t-1)
// All RAW pairs barrier-separated; msg loads 4-buffer rotated 3 steps ahead.
__global__ void __launch_bounds__(512, 2) fused_kernel(
    const float* __restrict__ msg,
    const u16* __restrict__ whhF8, const u16* __restrict__ wihF8,
    const u16* __restrict__ wembF8,
    const float* __restrict__ b_ih, const float* __restrict__ b_hh,
    const float* __restrict__ b_emb, const float* __restrict__ init_emb,
    const u16* __restrict__ wfc1F8, const float* __restrict__ b_fc1,
    const u16* __restrict__ wfc2F8, const float* __restrict__ b_fc2,
    float* __restrict__ out) {
    __shared__ u16 hlds[2][16 * 136];     // h double buffer, row stride 136
    __shared__ float epart[2][8][576];    // embed partials, dbuf, row stride 36
    __shared__ u16 xfrag[2][640];         // x bf16 A-frag staging, row stride 40
    __shared__ u16 hidl[16 * 264];        // FC1 out
    const int tid = threadIdx.x, w = tid >> 6, l = tid & 63;
    const int ln = l & 15, lh = l >> 4;
    const int wg = w & 3, wp = w >> 2;
    const int gb = blockIdx.x;

    for (int i = tid; i < 16 * 136; i += 512) hlds[0][i] = 0;

    // ---- resident weight fragments ----
    const s16x8* whhFv = (const s16x8*)whhF8;
    const s16x8* wihFv = (const s16x8*)wihF8;
    const s16x8* wembFv = (const s16x8*)wembF8;
    s16x8 wh[3][4], wi[3], we[2][2];
    float br, bz, bin, bgn;
    {
        #pragma unroll
        for (int g = 0; g < 3; g++) {
            int gt = wg + 4 * wp + 8 * g;
            #pragma unroll
            for (int kc = 0; kc < 4; kc++) wh[g][kc] = whhFv[(gt * 4 + kc) * 64 + l];
            wi[g] = wihFv[gt * 64 + l];
        }
        int c = wg * 16 + wp * 64 + ln;
        br  = b_ih[c] + b_hh[c];
        bz  = b_ih[128 + c] + b_hh[128 + c];
        bin = b_ih[256 + c];
        bgn = b_hh[256 + c];
        #pragma unroll
        for (int kk = 0; kk < 2; kk++) {
            we[kk][0] = wembFv[(2 * w + kk) * 64 + l];
            we[kk][1] = wembFv[(16 + 2 * w + kk) * 64 + l];
        }
    }
    const float bev = b_emb[tid & 31];

    // x_0 = init_emb broadcast (A-frag: lane l holds x[*][lh*8+j])
    s16x8 xinit;
    {
        Frag xi;
        #pragma unroll
        for (int j = 0; j < 8; j++) xi.q[j] = f2bf(init_emb[lh * 8 + j]);
        xinit = xi.v;
    }
    float hold[4] = {};
    // msg base: row (gb*16+ln), float offset (2w)*32 + lh*8
    const float* mrow = msg + (size_t)(gb * 16 + ln) * T_ * V_ + (2 * w) * 32 + lh * 8;
    f32x4 mb0[4], mb1[4], mb2[4], mb3[4];
#define LOADCOL(BUF, C) do {                                   \
    const float* p_ = mrow + (size_t)(C) * 512;                \
    BUF[0] = *(const f32x4*)(p_);                              \
    BUF[1] = *(const f32x4*)(p_ + 4);                          \
    BUF[2] = *(const f32x4*)(p_ + 32);                         \
    BUF[3] = *(const f32x4*)(p_ + 36);                         \
} while (0)

// embed partials of one msg column (held in MC regs) -> epart[PAR][w]
#define EMBED_STORE(MC, PAR) do {                               \
    f32x4 e0 = {0.f, 0.f, 0.f, 0.f}, e1 = {0.f, 0.f, 0.f, 0.f}; \
    _Pragma("unroll")                                           \
    for (int kk = 0; kk < 2; kk++) {                            \
        Frag fa;                                                \
        fa.u[0] = cvtpk(MC[2 * kk][0], MC[2 * kk][1]);          \
        fa.u[1] = cvtpk(MC[2 * kk][2], MC[2 * kk][3]);          \
        fa.u[2] = cvtpk(MC[2 * kk + 1][0], MC[2 * kk + 1][1]);  \
        fa.u[3] = cvtpk(MC[2 * kk + 1][2], MC[2 * kk + 1][3]);  \
        e0 = MFMA16(fa.v, we[kk][0], e0);                       \
        e1 = MFMA16(fa.v, we[kk][1], e1);                       \
    }                                                           \
    _Pragma("unroll")                                           \
    for (int i = 0; i < 4; i++) {                               \
        epart[PAR][w][(lh * 4 + i) * 36 + ln]      = e0[i];     \
        epart[PAR][w][(lh * 4 + i) * 36 + 16 + ln] = e1[i];     \
    }                                                           \
} while (0)

    // ---- prologue: partials of x_1 = emb(msg col 0) -> epart[1]; preload cols 1-3
    LOADCOL(mb3, 0);
    EMBED_STORE(mb3, 1);
    LOADCOL(mb0, 1); LOADCOL(mb1, 2); LOADCOL(mb2, 3);
    LDS_BARRIER();

    const int aoff = ln * 136 + lh * 8;
    const int colo = wg * 16 + wp * 64 + ln;
    const int fr = tid >> 5, fc = tid & 31, fo = fr * 36 + fc;

#define GRU_STEP(TT, MC, MN) do {                                              \
    const int t = (TT);                                                        \
    if (t <= 58) LOADCOL(MN, t + 4);                                           \
    const u16* hb = hlds[t & 1];                                               \
    s16x8 af0 = *(const s16x8*)(hb + aoff);                                    \
    s16x8 af1 = *(const s16x8*)(hb + aoff + 32);                               \
    s16x8 af2 = *(const s16x8*)(hb + aoff + 64);                               \
    s16x8 af3 = *(const s16x8*)(hb + aoff + 96);                               \
    s16x8 xc;                                                                  \
    if (t == 0) xc = xinit;                                                    \
    else xc = *(const s16x8*)(&xfrag[(t + 1) & 1][0] + ln * 40 + lh * 8);      \
    f32x4 ar  = {br, br, br, br};                                              \
    f32x4 az  = {bz, bz, bz, bz};                                              \
    f32x4 agn = {bgn, bgn, bgn, bgn};                                          \
    f32x4 ain = {bin, bin, bin, bin};                                          \
    ar  = MFMA16(xc, wi[0], ar);                                               \
    az  = MFMA16(xc, wi[1], az);                                               \
    ain = MFMA16(xc, wi[2], ain);                                              \
    ar  = MFMA16(af0, wh[0][0], ar);                                           \
    ar  = MFMA16(af1, wh[0][1], ar);                                           \
    ar  = MFMA16(af2, wh[0][2], ar);                                           \
    ar  = MFMA16(af3, wh[0][3], ar);                                           \
    az  = MFMA16(af0, wh[1][0], az);                                           \
    az  = MFMA16(af1, wh[1][1], az);                                           \
    az  = MFMA16(af2, wh[1][2], az);                                           \
    az  = MFMA16(af3, wh[1][3], az);                                           \
    agn = MFMA16(af0, wh[2][0], agn);                                          \
    agn = MFMA16(af1, wh[2][1], agn);                                          \
    agn = MFMA16(af2, wh[2][2], agn);                                          \
    agn = MFMA16(af3, wh[2][3], agn);                                          \
    u16* hw = hlds[(t + 1) & 1];                                               \
    float hn[4];                                                               \
    _Pragma("unroll")                                                          \
    for (int i = 0; i < 4; i++) {                                              \
        float rg = sigf(ar[i]);                                                \
        float zg = sigf(az[i]);                                                \
        float ng = tanhfast(ain[i] + rg * agn[i]);                             \
        hn[i] = zg * (hold[i] - ng) + ng;                                      \
        hold[i] = hn[i];                                                       \
    }                                                                          \
    {                                                                          \
        unsigned u01 = cvtpk(hn[0], hn[1]);                                    \
        unsigned u23 = cvtpk(hn[2], hn[3]);                                    \
        hw[(lh * 4 + 0) * 136 + colo] = (u16)(u01 & 0xFFFFu);                  \
        hw[(lh * 4 + 1) * 136 + colo] = (u16)(u01 >> 16);                      \
        hw[(lh * 4 + 2) * 136 + colo] = (u16)(u23 & 0xFFFFu);                  \
        hw[(lh * 4 + 3) * 136 + colo] = (u16)(u23 >> 16);                      \
    }                                                                          \
    if (t <= 61) EMBED_STORE(MC, t & 1);                                       \
    if (t <= 62) {                                                             \
        const float* eb = &epart[(t + 1) & 1][0][0];                           \
        float s = eb[fo]           + eb[576 + fo]     + eb[2 * 576 + fo]       \
                + eb[3 * 576 + fo] + eb[4 * 576 + fo] + eb[5 * 576 + fo]       \
                + eb[6 * 576 + fo] + eb[7 * 576 + fo] + bev;                   \
        xfrag[t & 1][fr * 40 + fc] = f2bf(s);                                  \
    }                                                                          \
    LDS_BARRIER();                                                             \
} while (0)

    for (int tt = 0; tt < 64; tt += 4) {
        GRU_STEP(tt + 0, mb0, mb3);
        GRU_STEP(tt + 1, mb1, mb0);
        GRU_STEP(tt + 2, mb2, mb1);
        GRU_STEP(tt + 3, mb3, mb2);
    }
#undef GRU_STEP
#undef LOADCOL
#undef EMBED_STORE

    // ---- FC1: hid = elu(h @ W_fc1^T + b_fc1), [16][256]; wave w: ot = 2w,2w+1
    const u16* hb = hlds[0];   // final h in buffer (63+1)&1 = 0
    s16x8 hf0 = *(const s16x8*)(hb + aoff);
    s16x8 hf1 = *(const s16x8*)(hb + aoff + 32);
    s16x8 hf2 = *(const s16x8*)(hb + aoff + 64);
    s16x8 hf3 = *(const s16x8*)(hb + aoff + 96);
    const s16x8* w1v = (const s16x8*)wfc1F8;
    #pragma unroll
    for (int q = 0; q < 2; q++) {
        int ot = 2 * w + q;
        float b1 = b_fc1[ot * 16 + ln];
        f32x4 a1 = {b1, b1, b1, b1};
        a1 = MFMA16(hf0, w1v[(ot * 4 + 0) * 64 + l], a1);
        a1 = MFMA16(hf1, w1v[(ot * 4 + 1) * 64 + l], a1);
        a1 = MFMA16(hf2, w1v[(ot * 4 + 2) * 64 + l], a1);
        a1 = MFMA16(hf3, w1v[(ot * 4 + 3) * 64 + l], a1);
        #pragma unroll
        for (int i = 0; i < 4; i++) {
            float v = a1[i];
            v = v > 0.0f ? v : (__expf(v) - 1.0f);
            hidl[(lh * 4 + i) * 264 + ot * 16 + ln] = f2bf(v);
        }
    }
    LDS_BARRIER();

    // ---- FC2: out = sigmoid(hid @ W_fc2^T + b_fc2); wave w: nt = 8w..8w+7
    s16x8 hf[8];
    #pragma unroll
    for (int kc = 0; kc < 8; kc++)
        hf[kc] = *(const s16x8*)(hidl + ln * 264 + kc * 32 + lh * 8);
    const s16x8* w2v = (const s16x8*)wfc2F8;
    #pragma unroll
    for (int q = 0; q < 8; q++) {
        int nt = 8 * w + q;
        float b2 = b_fc2[nt * 16 + ln];
        f32x4 a2 = {b2, b2, b2, b2};
        #pragma unroll
        for (int kc = 0; kc < 8; kc++)
            a2 = MFMA16(hf[kc], w2v[(nt * 8 + kc) * 64 + l], a2);
        #pragma unroll
        for (int i = 0; i < 4; i++)
            out[(size_t)(gb * 16 + lh * 4 + i) * 1024 + nt * 16 + ln] = sigf(a2[i]);
    }
}

extern "C" void kernel_launch(void* const* d_in, const int* in_sizes, int n_in,
                              void* d_out, int out_size, void* d_ws, size_t ws_size,
                              hipStream_t stream) {
    const float* message  = (const float*)d_in[0];
    const float* W_emb    = (const float*)d_in[1];
    const float* b_emb    = (const float*)d_in[2];
    const float* init_emb = (const float*)d_in[3];
    const float* W_ih     = (const float*)d_in[4];
    const float* W_hh     = (const float*)d_in[5];
    const float* b_ih     = (const float*)d_in[6];
    const float* b_hh     = (const float*)d_in[7];
    const float* W_fc1    = (const float*)d_in[8];
    const float* b_fc1    = (const float*)d_in[9];
    const float* W_fc2    = (const float*)d_in[10];
    const float* b_fc2    = (const float*)d_in[11];
    float* out = (float*)d_out;

    u16* whhF  = (u16*)d_ws;            // 24*4*64*8 = 49,152
    u16* wihF  = whhF  + 49152;         // 24*64*8   = 12,288
    u16* wembF = wihF  + 12288;         // 2*16*64*8 = 16,384
    u16* wfc1F = wembF + 16384;         // 16*4*64*8 = 32,768
    u16* wfc2F = wfc1F + 32768;         // 64*8*64*8 = 262,144  (total ~0.75 MB)

    hipLaunchKernelGGL(prep_kernel, dim3(256), dim3(256), 0, stream,
                       W_ih, W_hh, W_emb, W_fc1, W_fc2, wihF, whhF, wembF, wfc1F, wfc2F);
    hipLaunchKernelGGL(fused_kernel, dim3(256), dim3(512), 0, stream,
                       message, whhF, wihF, wembF, b_ih, b_hh, b_emb, init_emb,
                       wfc1F, b_fc1, wfc2F, b_fc2, out);
}